// Round 6
// baseline (664.317 us; speedup 1.0000x reference)
//
#include <hip/hip_runtime.h>
#include <math.h>

#define B_ROWS 512
#define D_DIM  512
#define C_CLS  100000
#define SCALE  64.0f
#define EPSN   1e-12f

#define NT 3125              // 100000/32 col tiles (exact); partials per row

typedef __attribute__((ext_vector_type(8))) short bf16x8;
typedef __attribute__((ext_vector_type(4))) float f32x4;

__device__ inline unsigned short f2bf(float f) {
    union { float f; unsigned int u; } v; v.f = f;
    unsigned int r = v.u + 0x7fffu + ((v.u >> 16) & 1u);
    return (unsigned short)(r >> 16);
}
__device__ inline float bf2f(unsigned short h) {
    union { unsigned int u; float f; } v; v.u = ((unsigned int)h) << 16;
    return v.f;
}

// ---------- fused prep: blocks [0,2048) scale-normalize W -> bf16,
//            blocks [2048,2176) normalize x -> bf16 ----------
__global__ void prep(const float* __restrict__ w, const float* __restrict__ x,
                     unsigned short* __restrict__ wn, unsigned short* __restrict__ xnb) {
    int wid  = threadIdx.x >> 6;
    int lane = threadIdx.x & 63;
    int bid  = blockIdx.x;
    if (bid < 2048) {
        for (int c = bid * 4 + wid; c < C_CLS; c += 8192) {
            const float4* wr = (const float4*)(w + (size_t)c * D_DIM);
            float4 a = wr[lane];
            float4 b = wr[lane + 64];
            float ss = a.x*a.x + a.y*a.y + a.z*a.z + a.w*a.w
                     + b.x*b.x + b.y*b.y + b.z*b.z + b.w*b.w;
            #pragma unroll
            for (int m = 1; m < 64; m <<= 1) ss += __shfl_xor(ss, m);
            float s = SCALE / fmaxf(sqrtf(ss), EPSN);
            ushort4 o0, o1;
            o0.x = f2bf(a.x*s); o0.y = f2bf(a.y*s); o0.z = f2bf(a.z*s); o0.w = f2bf(a.w*s);
            o1.x = f2bf(b.x*s); o1.y = f2bf(b.y*s); o1.z = f2bf(b.z*s); o1.w = f2bf(b.w*s);
            ushort4* orow = (ushort4*)(wn + (size_t)c * D_DIM);
            orow[lane]      = o0;
            orow[lane + 64] = o1;
        }
    } else {
        int r = (bid - 2048) * 4 + wid;   // 128 blocks x 4 waves = 512 rows
        const float4* xr = (const float4*)(x + (size_t)r * D_DIM);
        float4 a = xr[lane];
        float4 b = xr[lane + 64];
        float ss = a.x*a.x + a.y*a.y + a.z*a.z + a.w*a.w
                 + b.x*b.x + b.y*b.y + b.z*b.z + b.w*b.w;
        #pragma unroll
        for (int m = 1; m < 64; m <<= 1) ss += __shfl_xor(ss, m);
        float s = 1.0f / fmaxf(sqrtf(ss), EPSN);
        ushort4 o0, o1;
        o0.x = f2bf(a.x*s); o0.y = f2bf(a.y*s); o0.z = f2bf(a.z*s); o0.w = f2bf(a.w*s);
        o1.x = f2bf(b.x*s); o1.y = f2bf(b.y*s); o1.z = f2bf(b.z*s); o1.w = f2bf(b.w*s);
        ushort4* orow = (ushort4*)(xnb + (size_t)r * D_DIM);
        orow[lane]      = o0;
        orow[lane + 64] = o1;
    }
}

// ---------- persistent MFMA GEMM: A (64 rows x K=512) in LDS, one barrier.
// Wave tile = 64 rows x 32 cols; register double-buffered ks-pipeline:
// ks+1's 2 B global loads + 4 A ds_reads issue before ks's 8 MFMAs.
// Grid 512 = (xcd:8) x (rowgroup:8) x (colslice:8); 8 waves/block, 2 blocks/CU.
// A LDS swizzle: row r, 16B-chunk c at slot c ^ (r&7) -> uniform banks.
__global__ __launch_bounds__(512, 4) void gemm_ce(const unsigned short* __restrict__ xnb,
                                                  const unsigned short* __restrict__ wn,
                                                  float* __restrict__ partials) {
    __shared__ unsigned short Ash[64 * 512];   // 64 KB

    int tid  = threadIdx.x;
    int bid  = blockIdx.x;
    int x    = bid & 7;          // XCD (round-robin dispatch)
    int rg   = (bid >> 3) & 7;   // row group: rows rg*64 .. +63
    int cs   = bid >> 6;         // col slice 0..7
    int wid  = tid >> 6;
    int lane = tid & 63;
    int quad = lane >> 4;
    int lr   = lane & 15;

    // ---- stage A once: 64 rows x 64 chunks of 16B, xor-swizzled ----
    #pragma unroll
    for (int i = 0; i < 8; i++) {
        int ch = i * 512 + tid;          // 4096 chunks
        int r  = ch >> 6, c = ch & 63;
        *(uint4*)(Ash + r * 512 + ((c ^ (r & 7)) * 8)) =
            *(const uint4*)(xnb + (size_t)(rg * 64 + r) * D_DIM + c * 8);
    }
    __syncthreads();

    // A LDS read addresses for the 4 row-fragments (ushort offsets)
    int abase[4];
    #pragma unroll
    for (int rf = 0; rf < 4; rf++) {
        int r = rf * 16 + lr;
        abase[rf] = r * 512;
    }
    int axor = 0; // per-rf xor applied inline (r&7 == lr&7, same for all rf since rf*16 keeps low 3 bits)
    axor = (lr & 7);

    int worker = (x * 8 + cs) * 8 + wid;   // 0..511 within this rowgroup

    for (int ct = worker; ct < NT; ct += 512) {
        int c0 = ct * 32;
        const unsigned short* brow0 = wn + (size_t)(c0 + lr) * D_DIM + quad * 8;
        const unsigned short* brow1 = wn + (size_t)(c0 + 16 + lr) * D_DIM + quad * 8;

        f32x4 acc[4][2];
        #pragma unroll
        for (int rf = 0; rf < 4; rf++)
            #pragma unroll
            for (int cf = 0; cf < 2; cf++) {
                acc[rf][cf][0] = 0.f; acc[rf][cf][1] = 0.f;
                acc[rf][cf][2] = 0.f; acc[rf][cf][3] = 0.f;
            }

        bf16x8 Ab[2][4], Bb[2][2];
        // prologue: ks=0 into buffer 0
        Bb[0][0] = *(const bf16x8*)(brow0);
        Bb[0][1] = *(const bf16x8*)(brow1);
        #pragma unroll
        for (int rf = 0; rf < 4; rf++)
            Ab[0][rf] = *(const bf16x8*)(Ash + abase[rf] + ((quad ^ axor) * 8));

        #pragma unroll
        for (int ks = 0; ks < 16; ks++) {
            int cb = ks & 1, nb = cb ^ 1;
            if (ks < 15) {
                int kn = ks + 1;
                Bb[nb][0] = *(const bf16x8*)(brow0 + kn * 32);
                Bb[nb][1] = *(const bf16x8*)(brow1 + kn * 32);
                int sb = kn * 4;
                #pragma unroll
                for (int rf = 0; rf < 4; rf++)
                    Ab[nb][rf] = *(const bf16x8*)(Ash + abase[rf] + (((sb + quad) ^ axor) * 8));
            }
            #pragma unroll
            for (int rf = 0; rf < 4; rf++) {
                acc[rf][0] = __builtin_amdgcn_mfma_f32_16x16x32_bf16(Ab[cb][rf], Bb[cb][0], acc[rf][0], 0, 0, 0);
                acc[rf][1] = __builtin_amdgcn_mfma_f32_16x16x32_bf16(Ab[cb][rf], Bb[cb][1], acc[rf][1], 0, 0, 0);
            }
        }

        // epilogue: partial Σexp over this tile's 32 cols (|logit|<=64.2, no max needed)
        #pragma unroll
        for (int rf = 0; rf < 4; rf++) {
            #pragma unroll
            for (int rr = 0; rr < 4; rr++) {
                float e = expf(acc[rf][0][rr]) + expf(acc[rf][1][rr]);
                #pragma unroll
                for (int msk = 1; msk < 16; msk <<= 1) e += __shfl_xor(e, msk);
                if (lr == 0) {
                    int row_g = rg * 64 + rf * 16 + quad * 4 + rr;
                    partials[(size_t)row_g * NT + ct] = e;
                }
            }
        }
    }
}

// ---------- fused: label logit + sum partials -> loss ----------
__global__ void reduce_loss(const float* __restrict__ partials,
                            const unsigned short* __restrict__ xnb,
                            const unsigned short* __restrict__ wn,
                            const int* __restrict__ label,
                            float* __restrict__ out) {
    __shared__ float ssum[256], sdot[256];
    int row = blockIdx.x, tid = threadIdx.x;

    float d = 0.f;
    int lab = label[row];
    if (tid < 128) {
        ushort4 xv = ((const ushort4*)(xnb + (size_t)row * D_DIM))[tid];
        ushort4 wv = ((const ushort4*)(wn + (size_t)lab * D_DIM))[tid];
        d = bf2f(xv.x) * bf2f(wv.x) + bf2f(xv.y) * bf2f(wv.y)
          + bf2f(xv.z) * bf2f(wv.z) + bf2f(xv.w) * bf2f(wv.w);
    }
    sdot[tid] = d;

    float s = 0.f;
    for (int idx = tid; idx < NT; idx += 256)
        s += partials[(size_t)row * NT + idx];
    ssum[tid] = s;
    __syncthreads();
    for (int off = 128; off > 0; off >>= 1) {
        if (tid < off) {
            ssum[tid] += ssum[tid + off];
            sdot[tid] += sdot[tid + off];
        }
        __syncthreads();
    }
    if (tid == 0)
        atomicAdd(out, (logf(ssum[0]) - sdot[0]) * (1.0f / (float)B_ROWS));
}

extern "C" void kernel_launch(void* const* d_in, const int* in_sizes, int n_in,
                              void* d_out, int out_size, void* d_ws, size_t ws_size,
                              hipStream_t stream) {
    const float* x     = (const float*)d_in[0];
    const float* w     = (const float*)d_in[1];
    const int*   label = (const int*)d_in[2];
    float* out = (float*)d_out;

    char* ws = (char*)d_ws;
    unsigned short* xnb = (unsigned short*)ws;                 // 524288 B
    float* partials     = (float*)(ws + 524288);               // 512*3125*4 = 6400000 B (ends 6924288)
    unsigned short* wn  = (unsigned short*)(ws + 6924288);     // 102400000 B (ends 109324288)

    hipMemsetAsync(d_out, 0, sizeof(float), stream);
    prep<<<2176, 256, 0, stream>>>(w, x, wn, xnb);
    gemm_ce<<<512, 512, 0, stream>>>(xnb, wn, partials);
    reduce_loss<<<B_ROWS, 256, 0, stream>>>(partials, xnb, wn, label, out);
}